// Round 1
// baseline (174.598 us; speedup 1.0000x reference)
//
#include <hip/hip_runtime.h>

// GCN imputation, collapsed form (C=1):
//   a[g,d]  = sum_e norm_e * x[g,src_e]   (+ self-loop dinv^2 * x[g,d])
//   z[g,n]  = sum_f relu(W1[f]*a + b1[f]) * W2[f]
//   out[g,d]= sum_e norm_e * z[g,src_e] + dinv[d]^2 * z[g,d] + b2
//   out     = mask ? x : out
// Layout trick: all per-node vectors stored node-major (n*64+g) so one wave
// handles one edge with fully coalesced 256B read + 256B atomic.

#define G 64   // B*S = 2*32 replicas sharing one graph

// --- deg[d] += w[e] over edges (self loop handled as +1 later) ---
__global__ void deg_kernel(const int* __restrict__ dst,
                           const float* __restrict__ w,
                           float* __restrict__ deg, int E) {
    int e = blockIdx.x * blockDim.x + threadIdx.x;
    if (e < E) atomicAdd(&deg[dst[e]], w[e]);
}

// --- dinv[n] = rsqrt(deg[n] + 1)  (in place; +1 = self-loop weight) ---
__global__ void dinv_kernel(float* __restrict__ deg, int N) {
    int n = blockIdx.x * blockDim.x + threadIdx.x;
    if (n < N) deg[n] = rsqrtf(deg[n] + 1.0f);
}

// --- xt[n*64+g] = x[g*N+n];  a[n*64+g] = dinv[n]^2 * x  (self-loop seed) ---
__global__ void transpose_init(const float* __restrict__ x,
                               const float* __restrict__ dinv,
                               float* __restrict__ xt,
                               float* __restrict__ a, int N) {
    int t = blockIdx.x * blockDim.x + threadIdx.x;  // t = n*64 + g
    if (t >= N * G) return;
    int n = t >> 6, g = t & 63;
    float v = x[g * N + n];
    xt[t] = v;
    float di = dinv[n];
    a[t] = di * di * v;
}

// --- one wave per edge: out[d*64+g] += dinv[s]*w*dinv[d] * in[s*64+g] ---
__global__ void edge_pass(const int* __restrict__ src,
                          const int* __restrict__ dst,
                          const float* __restrict__ w,
                          const float* __restrict__ dinv,
                          const float* __restrict__ in_ng,
                          float* __restrict__ out_ng, int E) {
    int wid  = (blockIdx.x * blockDim.x + threadIdx.x) >> 6;  // edge id
    int lane = threadIdx.x & 63;                              // replica g
    if (wid >= E) return;
    int s = src[wid], d = dst[wid];
    float nrm = dinv[s] * w[wid] * dinv[d];
    float v = nrm * in_ng[s * G + lane];
    atomicAdd(&out_ng[d * G + lane], v);
}

// --- z = phi(a) in place; o = b2 + dinv^2 * z  (pass-2 self-loop seed) ---
__global__ void phi_kernel(float* __restrict__ az,          // a in, z out (in place)
                           const float* __restrict__ dinv,
                           const float* __restrict__ W1,    // (1,32)
                           const float* __restrict__ b1,    // (32,)
                           const float* __restrict__ W2,    // (32,1)
                           const float* __restrict__ b2,    // (1,)
                           float* __restrict__ o, int N) {
    int t = blockIdx.x * blockDim.x + threadIdx.x;  // t = n*64 + g
    if (t >= N * G) return;
    int n = t >> 6;
    float av = az[t];
    float acc = 0.0f;
#pragma unroll
    for (int f = 0; f < 32; ++f) {
        float h = fmaf(W1[f], av, b1[f]);
        acc = fmaf(fmaxf(h, 0.0f), W2[f], acc);
    }
    az[t] = acc;
    float di = dinv[n];
    o[t] = fmaf(di * di, acc, b2[0]);
}

// --- out[g*N+n] = mask ? x : o[n*64+g] ---
__global__ void finalize(const float* __restrict__ x,
                         const int* __restrict__ mask,
                         const float* __restrict__ o,
                         float* __restrict__ out, int N, int total) {
    int t = blockIdx.x * blockDim.x + threadIdx.x;  // t = g*N + n
    if (t >= total) return;
    int g = t / N;
    int n = t - g * N;
    out[t] = mask[t] ? x[t] : o[n * G + g];
}

extern "C" void kernel_launch(void* const* d_in, const int* in_sizes, int n_in,
                              void* d_out, int out_size, void* d_ws, size_t ws_size,
                              hipStream_t stream) {
    const float* x    = (const float*)d_in[0];   // (2,32,N,1) -> g-major (64,N)
    const int*   mask = (const int*)  d_in[1];   // bool as int32 (harness rule)
    const int*   eidx = (const int*)  d_in[2];   // (2,E)
    const float* ew   = (const float*)d_in[3];   // (E,)
    const float* W1   = (const float*)d_in[4];   // (1,32)
    const float* b1   = (const float*)d_in[5];   // (32,)
    const float* W2   = (const float*)d_in[6];   // (32,1)
    const float* b2   = (const float*)d_in[7];   // (1,)
    float* out = (float*)d_out;

    const int E = in_sizes[3];          // 160000
    const int N = in_sizes[0] / G;      // 10000
    const int total = N * G;            // 640000

    const int* src = eidx;
    const int* dst = eidx + E;

    // workspace layout (floats)
    float* ws   = (float*)d_ws;
    float* deg  = ws;                   // N (becomes dinv in place)
    float* xt   = ws + 16384;           // total
    float* az   = xt + total;           // total (a, then z in place)
    float* o    = az + total;           // total

    hipMemsetAsync(deg, 0, N * sizeof(float), stream);

    deg_kernel<<<(E + 255) / 256, 256, 0, stream>>>(dst, ew, deg, E);
    dinv_kernel<<<(N + 255) / 256, 256, 0, stream>>>(deg, N);
    transpose_init<<<(total + 255) / 256, 256, 0, stream>>>(x, deg, xt, az, N);

    // pass 1: 4 waves (edges) per 256-thread block
    edge_pass<<<(E + 3) / 4, 256, 0, stream>>>(src, dst, ew, deg, xt, az, E);

    phi_kernel<<<(total + 255) / 256, 256, 0, stream>>>(az, deg, W1, b1, W2, b2, o, N);

    // pass 2
    edge_pass<<<(E + 3) / 4, 256, 0, stream>>>(src, dst, ew, deg, az, o, E);

    finalize<<<(total + 255) / 256, 256, 0, stream>>>(x, mask, o, out, N, total);
}

// Round 2
// 170.324 us; speedup vs baseline: 1.0251x; 1.0251x over previous
//
#include <hip/hip_runtime.h>

// GCN imputation, collapsed form (C=1), CSR-gather version (no float atomics):
//   deg[d]  = sum_{e: dst=d} w_e            (+1 self-loop at rsqrt)
//   dinv    = rsqrt(deg+1)
//   CSR: incoming edges per dst node (hist -> scan -> scatter), entry = {src, norm}
//   a[d,g]  = sum_in norm * xt[s,g] + dinv[d]^2 * xt[d,g]
//   z[d,g]  = phi(a) = sum_f relu(W1[f]*a+b1[f])*W2[f]      (fused into gather1)
//   o[d,g]  = sum_in norm * z[s,g] + dinv[d]^2 * z[d,g] + b2
//   out     = mask ? x : o   (tiled transpose back to g-major)
// All per-node vectors node-major (n*64+g): one wave per node, 256B coalesced.

#define G 64   // B*S replicas sharing one graph

// --- cnt[d] += 1; deg[d] += w  (int + float atomics, E ops each) ---
__global__ void hist_deg_kernel(const int* __restrict__ dst,
                                const float* __restrict__ w,
                                int* __restrict__ cnt,
                                float* __restrict__ deg, int E) {
    int e = blockIdx.x * blockDim.x + threadIdx.x;
    if (e < E) {
        int d = dst[e];
        atomicAdd(&cnt[d], 1);
        atomicAdd(&deg[d], w[e]);
    }
}

// --- single block: exclusive scan cnt->ptr, cur=ptr, dinv=rsqrt(deg+1) ---
__global__ void __launch_bounds__(1024)
scan_dinv_kernel(int* __restrict__ cnt,        // in: counts, out: cursor(=ptr)
                 float* __restrict__ deg,      // in: deg, out: dinv (in place)
                 int* __restrict__ ptr, int N) {
    __shared__ int sums[1024];
    const int CH = 10;                         // 1024*10 >= 10000
    int tid = threadIdx.x;
    int begin = tid * CH;
    int end = begin + CH; if (end > N) end = N;
    int c[CH];
    int local = 0;
    for (int i = begin; i < end; ++i) { c[i - begin] = cnt[i]; local += c[i - begin]; }
    sums[tid] = local;
    __syncthreads();
    for (int off = 1; off < 1024; off <<= 1) {   // Hillis-Steele inclusive
        int v = sums[tid];
        int add = (tid >= off) ? sums[tid - off] : 0;
        __syncthreads();
        sums[tid] = v + add;
        __syncthreads();
    }
    int run = (tid > 0) ? sums[tid - 1] : 0;     // exclusive base
    for (int i = begin; i < end; ++i) {
        ptr[i] = run;
        cnt[i] = run;                            // cursor for scatter
        run += c[i - begin];
        deg[i] = rsqrtf(deg[i] + 1.0f);          // dinv in place
    }
    if (tid == 1023) ptr[N] = sums[1023];
}

// --- scatter edges into CSR: csr[pos] = {src, bits(dinv[s]*w*dinv[d])} ---
__global__ void scatter_kernel(const int* __restrict__ src,
                               const int* __restrict__ dst,
                               const float* __restrict__ w,
                               const float* __restrict__ dinv,
                               int* __restrict__ cur,
                               int2* __restrict__ csr, int E) {
    int e = blockIdx.x * blockDim.x + threadIdx.x;
    if (e < E) {
        int s = src[e], d = dst[e];
        int pos = atomicAdd(&cur[d], 1);
        float nrm = dinv[s] * w[e] * dinv[d];
        csr[pos] = make_int2(s, __float_as_int(nrm));
    }
}

// --- tiled transpose x (g-major) -> xt (node-major) ---
__global__ void transpose_x(const float* __restrict__ x,
                            float* __restrict__ xt, int N) {
    __shared__ float tile[64][65];
    int n0 = blockIdx.x * 64;
    int lane = threadIdx.x & 63, quad = threadIdx.x >> 6;
#pragma unroll
    for (int i = 0; i < 16; ++i) {
        int g = quad + i * 4;
        int n = n0 + lane;
        if (n < N) tile[g][lane] = x[g * N + n];       // coalesced read
    }
    __syncthreads();
#pragma unroll
    for (int i = 0; i < 16; ++i) {
        int nl = quad + i * 4;
        int n = n0 + nl;
        if (n < N) xt[n * 64 + lane] = tile[lane][nl]; // coalesced write
    }
}

// --- wave per node: a = self + sum_in; z = phi(a); store z node-major ---
__global__ void gather1_phi(const int2* __restrict__ csr,
                            const int* __restrict__ ptr,
                            const float* __restrict__ dinv,
                            const float* __restrict__ xt,
                            const float* __restrict__ W1,
                            const float* __restrict__ b1,
                            const float* __restrict__ W2,
                            float* __restrict__ z, int N) {
    int node = blockIdx.x * 4 + (threadIdx.x >> 6);
    int lane = threadIdx.x & 63;
    if (node >= N) return;
    int k0 = ptr[node], k1 = ptr[node + 1];
    float di = dinv[node];
    float acc = di * di * xt[node * 64 + lane];
    for (int k = k0; k < k1; ++k) {
        int2 en = csr[k];
        acc = fmaf(__int_as_float(en.y), xt[en.x * 64 + lane], acc);
    }
    float zv = 0.0f;
#pragma unroll
    for (int f = 0; f < 32; ++f) {
        float h = fmaf(W1[f], acc, b1[f]);
        zv = fmaf(fmaxf(h, 0.0f), W2[f], zv);
    }
    z[node * 64 + lane] = zv;
}

// --- wave per node: o = b2 + self + sum_in over z ---
__global__ void gather2(const int2* __restrict__ csr,
                        const int* __restrict__ ptr,
                        const float* __restrict__ dinv,
                        const float* __restrict__ z,
                        const float* __restrict__ b2,
                        float* __restrict__ o, int N) {
    int node = blockIdx.x * 4 + (threadIdx.x >> 6);
    int lane = threadIdx.x & 63;
    if (node >= N) return;
    int k0 = ptr[node], k1 = ptr[node + 1];
    float di = dinv[node];
    float acc = fmaf(di * di, z[node * 64 + lane], b2[0]);
    for (int k = k0; k < k1; ++k) {
        int2 en = csr[k];
        acc = fmaf(__int_as_float(en.y), z[en.x * 64 + lane], acc);
    }
    o[node * 64 + lane] = acc;
}

// --- tiled: out[g*N+n] = mask ? x : o[n*64+g] ---
__global__ void finalize_t(const float* __restrict__ x,
                           const int* __restrict__ mask,
                           const float* __restrict__ o,
                           float* __restrict__ out, int N) {
    __shared__ float tile[64][65];
    int n0 = blockIdx.x * 64;
    int lane = threadIdx.x & 63, quad = threadIdx.x >> 6;
#pragma unroll
    for (int i = 0; i < 16; ++i) {
        int nl = quad + i * 4;
        int n = n0 + nl;
        if (n < N) tile[nl][lane] = o[n * 64 + lane];  // coalesced read
    }
    __syncthreads();
#pragma unroll
    for (int i = 0; i < 16; ++i) {
        int g = quad + i * 4;
        int n = n0 + lane;
        if (n < N) {
            int idx = g * N + n;
            out[idx] = mask[idx] ? x[idx] : tile[lane][g];  // coalesced
        }
    }
}

extern "C" void kernel_launch(void* const* d_in, const int* in_sizes, int n_in,
                              void* d_out, int out_size, void* d_ws, size_t ws_size,
                              hipStream_t stream) {
    const float* x    = (const float*)d_in[0];   // (2,32,N,1) -> g-major (64,N)
    const int*   mask = (const int*)  d_in[1];
    const int*   eidx = (const int*)  d_in[2];   // (2,E)
    const float* ew   = (const float*)d_in[3];
    const float* W1   = (const float*)d_in[4];
    const float* b1   = (const float*)d_in[5];
    const float* W2   = (const float*)d_in[6];
    const float* b2   = (const float*)d_in[7];
    float* out = (float*)d_out;

    const int E = in_sizes[3];          // 160000
    const int N = in_sizes[0] / G;      // 10000
    const int total = N * G;

    const int* src = eidx;
    const int* dst = eidx + E;

    // workspace layout (byte offsets, 1 KiB aligned)
    char* ws = (char*)d_ws;
    int*   cnt  = (int*)  (ws);             // N ints (count -> cursor)
    float* dinv = (float*)(ws + 40960);     // N floats (deg -> dinv in place)
    int*   ptr  = (int*)  (ws + 81920);     // N+1 ints
    int2*  csr  = (int2*) (ws + 122880);    // E int2 (1.28 MB)
    float* xt   = (float*)(ws + 1404928);   // total floats (2.56 MB)
    float* z    = xt + total;
    float* o    = z + total;

    // zero cnt + deg in one memset (adjacent regions)
    hipMemsetAsync(ws, 0, 81920, stream);

    hist_deg_kernel<<<(E + 255) / 256, 256, 0, stream>>>(dst, ew, cnt, (float*)dinv, E);
    scan_dinv_kernel<<<1, 1024, 0, stream>>>(cnt, dinv, ptr, N);
    scatter_kernel<<<(E + 255) / 256, 256, 0, stream>>>(src, dst, ew, dinv, cnt, csr, E);
    transpose_x<<<(N + 63) / 64, 256, 0, stream>>>(x, xt, N);
    gather1_phi<<<(N + 3) / 4, 256, 0, stream>>>(csr, ptr, dinv, xt, W1, b1, W2, z, N);
    gather2<<<(N + 3) / 4, 256, 0, stream>>>(csr, ptr, dinv, z, b2, o, N);
    finalize_t<<<(N + 63) / 64, 256, 0, stream>>>(x, mask, o, out, N);
}